// Round 14
// baseline (871.896 us; speedup 1.0000x reference)
//
#include <hip/hip_runtime.h>
#include <cstdint>
#include <cstddef>

typedef unsigned short u16;
typedef __attribute__((ext_vector_type(8))) short bf16x8;
typedef __attribute__((ext_vector_type(4))) float f32x4;

namespace {
constexpr int BATCH = 4;
constexpr int SEQ   = 2048;
constexpr int DM    = 1024;
constexpr int NH    = 16;
constexpr int HDIM  = 64;
constexpr int NL    = 2;
constexpr int DFF   = 4096;
constexpr int MROWS = BATCH * SEQ;   // 8192
constexpr int WIN   = 6;             // band half-width -> 13 keys max

constexpr size_t OFF_H    = 0;                       // 32 MiB fp32 residual
constexpr size_t OFF_ABUF = (size_t)32 << 20;        // 16 MiB bf16 (hn / attn out)
constexpr size_t OFF_BBUF = (size_t)48 << 20;        // 64 MiB bf16 (qkv / ff1)
constexpr size_t OFF_WBUF = (size_t)112 << 20;       //  8 MiB bf16 (per-GEMM weight)
constexpr size_t WS_REQUIRED = (size_t)120 << 20;

constexpr int SLOT = 384 * 64;       // u16 per LDS slot: A 256x64 + B 128x64
}

static __device__ __forceinline__ float b2f(u16 u) {
    return __builtin_bit_cast(float, (unsigned int)u << 16);
}
static __device__ __forceinline__ u16 f2b(float f) {
    unsigned int u = __builtin_bit_cast(unsigned int, f);
    u += 0x7FFFu + ((u >> 16) & 1u);   // RNE
    return (u16)(u >> 16);
}

// ---------------- fallback (ws too small): wrong answer but no OOB ----------------
__global__ __launch_bounds__(256) void fallback_k(const float* __restrict__ x,
                                                  float* __restrict__ out, int n) {
    int i = blockIdx.x * 256 + threadIdx.x;
    if (i < n) out[i] = x[i];
}

// ---------------- fp32 -> bf16 weight conversion ----------------
__global__ __launch_bounds__(256) void f2b_k(const float* __restrict__ in,
                                             u16* __restrict__ out, int n4) {
    int i = blockIdx.x * 256 + threadIdx.x;
    if (i < n4) {
        float4 v = ((const float4*)in)[i];
        unsigned int lo = (unsigned int)f2b(v.x) | ((unsigned int)f2b(v.y) << 16);
        unsigned int hi = (unsigned int)f2b(v.z) | ((unsigned int)f2b(v.w) << 16);
        ((uint2*)out)[i] = make_uint2(lo, hi);
    }
}

// ---------------- LayerNorm (row of 1024), fp32 in -> bf16 out ----------------
__global__ __launch_bounds__(256) void ln_k(const float* __restrict__ x,
                                            const float* __restrict__ g,
                                            const float* __restrict__ b,
                                            u16* __restrict__ out) {
    __shared__ float red[8];
    const int row = blockIdx.x;
    const float4 v = ((const float4*)(x + (size_t)row * DM))[threadIdx.x];
    float s1 = v.x + v.y + v.z + v.w;
    float s2 = v.x * v.x + v.y * v.y + v.z * v.z + v.w * v.w;
    #pragma unroll
    for (int o = 32; o; o >>= 1) {
        s1 += __shfl_xor(s1, o);
        s2 += __shfl_xor(s2, o);
    }
    const int wid = threadIdx.x >> 6, lane = threadIdx.x & 63;
    if (lane == 0) { red[wid] = s1; red[4 + wid] = s2; }
    __syncthreads();
    s1 = red[0] + red[1] + red[2] + red[3];
    s2 = red[4] + red[5] + red[6] + red[7];
    const float mu  = s1 * (1.0f / DM);
    const float var = s2 * (1.0f / DM) - mu * mu;
    const float inv = rsqrtf(var + 1e-5f);
    const float4 gg = ((const float4*)g)[threadIdx.x];
    const float4 bb = ((const float4*)b)[threadIdx.x];
    unsigned int lo = (unsigned int)f2b((v.x - mu) * inv * gg.x + bb.x)
                    | ((unsigned int)f2b((v.y - mu) * inv * gg.y + bb.y) << 16);
    unsigned int hi = (unsigned int)f2b((v.z - mu) * inv * gg.z + bb.z)
                    | ((unsigned int)f2b((v.w - mu) * inv * gg.w + bb.w) << 16);
    ((uint2*)(out + (size_t)row * DM))[threadIdx.x] = make_uint2(lo, hi);
}

// ---------------- banded attention v2: lane = query, serial in-lane dots ----------
__global__ __launch_bounds__(64, 2) void attn_k(const u16* __restrict__ qkv,
                                                const unsigned char* __restrict__ kpm,
                                                u16* __restrict__ out) {
    __shared__ u16 kv[76 * 68];        // 76 rows x 64 dims, row stride 68 u16 (136B)
    __shared__ float p_s[13 * 64];
    const int lane = threadIdx.x;      // query within tile
    const int bid  = blockIdx.x;
    const int qt = bid & (SEQ / 64 - 1);         // 32 tiles
    const int h  = (bid >> 5) & (NH - 1);
    const int b  = bid >> 9;
    const int t0 = qt * 64;
    const int t  = t0 + lane;
    const size_t rstride = 3 * DM;

    const u16* qbase = qkv + ((size_t)b * SEQ + t) * rstride + h * HDIM;
    float q[64];
    #pragma unroll
    for (int c = 0; c < 8; ++c) {
        uint4 v = *(const uint4*)(qbase + c * 8);
        unsigned int w0 = v.x, w1 = v.y, w2 = v.z, w3 = v.w;
        q[c*8+0] = b2f((u16)(w0 & 0xffff)) * 0.125f;
        q[c*8+1] = b2f((u16)(w0 >> 16))    * 0.125f;
        q[c*8+2] = b2f((u16)(w1 & 0xffff)) * 0.125f;
        q[c*8+3] = b2f((u16)(w1 >> 16))    * 0.125f;
        q[c*8+4] = b2f((u16)(w2 & 0xffff)) * 0.125f;
        q[c*8+5] = b2f((u16)(w2 >> 16))    * 0.125f;
        q[c*8+6] = b2f((u16)(w3 & 0xffff)) * 0.125f;
        q[c*8+7] = b2f((u16)(w3 >> 16))    * 0.125f;
    }

    auto stage = [&](int which) {
        const u16* src0 = qkv + ((size_t)b * SEQ) * rstride + which * DM + h * HDIM;
        #pragma unroll
        for (int it = 0; it < 10; ++it) {
            int g = it * 64 + lane;                // 16B chunk id, 608 total
            if (g < 608) {
                int row = g >> 3, cc = g & 7;
                int j = t0 - 6 + row;
                j = min(max(j, 0), SEQ - 1);
                uint4 v = *(const uint4*)(src0 + (size_t)j * rstride + cc * 8);
                *(uint2*)(kv + row * 68 + cc * 8)     = make_uint2(v.x, v.y);
                *(uint2*)(kv + row * 68 + cc * 8 + 4) = make_uint2(v.z, v.w);
            }
        }
    };

    stage(1);
    __syncthreads();
    for (int u = 0; u < 13; ++u) {
        const u16* krow = kv + (lane + u) * 68;
        float s = 0.f;
        #pragma unroll
        for (int c = 0; c < 16; ++c) {
            uint2 v = *(const uint2*)(krow + c * 4);
            s += q[c*4+0] * b2f((u16)(v.x & 0xffff));
            s += q[c*4+1] * b2f((u16)(v.x >> 16));
            s += q[c*4+2] * b2f((u16)(v.y & 0xffff));
            s += q[c*4+3] * b2f((u16)(v.y >> 16));
        }
        int j = t - WIN + u;
        bool ok = (j >= 0) && (j < SEQ);
        if (ok && kpm[b * SEQ + j]) ok = false;
        p_s[u * 64 + lane] = ok ? s : -1e30f;
    }

    float mx = -1e30f;
    for (int u = 0; u < 13; ++u) mx = fmaxf(mx, p_s[u * 64 + lane]);
    float den = 0.f;
    for (int u = 0; u < 13; ++u) {
        float e = __expf(p_s[u * 64 + lane] - mx);
        p_s[u * 64 + lane] = e;
        den += e;
    }
    const float inv = 1.0f / den;

    __syncthreads();
    stage(2);
    __syncthreads();
    u16* orow = out + ((size_t)b * SEQ + t) * DM + h * HDIM;
    #pragma unroll
    for (int dc = 0; dc < 4; ++dc) {
        float o[16] = {};
        for (int u = 0; u < 13; ++u) {
            const float p = p_s[u * 64 + lane];
            const u16* vrow = kv + (lane + u) * 68 + dc * 16;
            #pragma unroll
            for (int c = 0; c < 4; ++c) {
                uint2 v = *(const uint2*)(vrow + c * 4);
                o[c*4+0] += p * b2f((u16)(v.x & 0xffff));
                o[c*4+1] += p * b2f((u16)(v.x >> 16));
                o[c*4+2] += p * b2f((u16)(v.y & 0xffff));
                o[c*4+3] += p * b2f((u16)(v.y >> 16));
            }
        }
        unsigned int pk[8];
        #pragma unroll
        for (int i = 0; i < 8; ++i)
            pk[i] = (unsigned int)f2b(o[2*i] * inv)
                  | ((unsigned int)f2b(o[2*i+1] * inv) << 16);
        *(uint4*)(orow + dc * 16)     = make_uint4(pk[0], pk[1], pk[2], pk[3]);
        *(uint4*)(orow + dc * 16 + 8) = make_uint4(pk[4], pk[5], pk[6], pk[7]);
    }
}

// ---------------- bf16 NT GEMM v2: 256x128 tile, BK=64, 3-slot ring, counted vmcnt
// C[m,n] = sum_k A[m,k] * Bw[n,k].  8 waves (4M x 2N), per-wave 64x64 output.
// Pipeline: while computing tile t (slot t%3), prefetch tile t+2 (slot (t+2)%3);
// end-of-iter s_waitcnt vmcnt(6) guarantees tile t+1 landed (T3+T4). Every ds_read
// feeds an MFMA in its phase -> lgkm-drained before the final barrier => the slot
// reused 2 iterations later is safe. T2 swizzle: linear global_load_lds dest,
// inverse-swizzled source, XOR'd read (rule #21).  T5 setprio around MFMA clusters.
// EPI 0: +bias -> bf16 ; EPI 1: +bias, exact gelu -> bf16 ; EPI 2: +bias, +res -> fp32
template <int EPI>
__global__ __launch_bounds__(512, 2) void gemm_nt(const u16* __restrict__ A,
                                                  const u16* __restrict__ Bw,
                                                  const float* __restrict__ bias,
                                                  const float* __restrict__ res,
                                                  float* __restrict__ outf,
                                                  u16* __restrict__ outb,
                                                  int M, int N, int K) {
    __shared__ u16 lds[3 * SLOT];      // 144 KiB
    const int tid  = threadIdx.x;
    const int lane = tid & 63;
    const int wid  = tid >> 6;         // 0..7
    const int wm = wid >> 1;           // 0..3 -> rows wm*64
    const int wn = wid & 1;            // 0..1 -> cols wn*64
    const int r = lane & 15, quad = lane >> 4;
    const int row0a = blockIdx.y * 256;
    const int row0b = blockIdx.x * 128;
    const int nt = K >> 6;

    // precomputed staging sources/dests (6 x 16B chunks per thread per K-tile)
    const u16* gsrc[6];
    int dofs[6];
    #pragma unroll
    for (int s4 = 0; s4 < 4; ++s4) {           // A: 256x64 = 2048 chunks
        int e8 = s4 * 512 + tid;
        int rw = e8 >> 3, sl = e8 & 7, ssl = sl ^ (rw & 7);
        gsrc[s4] = A + (size_t)(row0a + rw) * K + ssl * 8;
        dofs[s4] = e8 * 8;
    }
    #pragma unroll
    for (int s4 = 0; s4 < 2; ++s4) {           // B: 128x64 = 1024 chunks
        int e8 = s4 * 512 + tid;
        int rw = e8 >> 3, sl = e8 & 7, ssl = sl ^ (rw & 7);
        gsrc[4 + s4] = Bw + (size_t)(row0b + rw) * K + ssl * 8;
        dofs[4 + s4] = 256 * 64 + e8 * 8;
    }
    auto stage = [&](u16* base, int k0) {
        #pragma unroll
        for (int i = 0; i < 6; ++i)
            __builtin_amdgcn_global_load_lds(
                (const __attribute__((address_space(1))) void*)(gsrc[i] + k0),
                (__attribute__((address_space(3))) void*)(base + dofs[i]), 16, 0, 0);
    };

    // prologue: stage tiles 0 and 1
    stage(lds, 0);
    if (nt > 1) stage(lds + SLOT, 64);
    if (nt > 2) asm volatile("s_waitcnt vmcnt(6)" ::: "memory");
    else        asm volatile("s_waitcnt vmcnt(0)" ::: "memory");
    __builtin_amdgcn_s_barrier();

    f32x4 acc[4][4] = {};
    int cur = 0, pre = 2, kpre = 128;
    for (int t = 0; t < nt; ++t) {
        const u16* As = lds + cur * SLOT;
        const u16* Bs = As + 256 * 64;
        const bool doPre = (t + 2 < nt);
        if (doPre) stage(lds + pre * SLOT, kpre);

        // ---- phase 1: all B frags + A frags (m-half 0) ----
        bf16x8 bfg[2][4], af[2][2];
        #pragma unroll
        for (int kk = 0; kk < 2; ++kk) {
            #pragma unroll
            for (int ni = 0; ni < 4; ++ni) {
                int rw = wn * 64 + ni * 16 + r;
                int sl = (kk * 4 + quad) ^ (rw & 7);
                bfg[kk][ni] = *(const bf16x8*)(Bs + rw * 64 + sl * 8);
            }
            #pragma unroll
            for (int mi = 0; mi < 2; ++mi) {
                int rw = wm * 64 + mi * 16 + r;
                int sl = (kk * 4 + quad) ^ (rw & 7);
                af[kk][mi] = *(const bf16x8*)(As + rw * 64 + sl * 8);
            }
        }
        __builtin_amdgcn_s_barrier();
        __builtin_amdgcn_s_setprio(1);
        #pragma unroll
        for (int mi = 0; mi < 2; ++mi)
            #pragma unroll
            for (int ni = 0; ni < 4; ++ni)
                #pragma unroll
                for (int kk = 0; kk < 2; ++kk)
                    acc[mi][ni] = __builtin_amdgcn_mfma_f32_16x16x32_bf16(
                        af[kk][mi], bfg[kk][ni], acc[mi][ni], 0, 0, 0);
        __builtin_amdgcn_s_setprio(0);
        __builtin_amdgcn_s_barrier();

        // ---- phase 2: A frags (m-half 1), B reused from registers ----
        bf16x8 af2[2][2];
        #pragma unroll
        for (int kk = 0; kk < 2; ++kk)
            #pragma unroll
            for (int mi = 0; mi < 2; ++mi) {
                int rw = wm * 64 + (mi + 2) * 16 + r;
                int sl = (kk * 4 + quad) ^ (rw & 7);
                af2[kk][mi] = *(const bf16x8*)(As + rw * 64 + sl * 8);
            }
        __builtin_amdgcn_s_barrier();
        __builtin_amdgcn_s_setprio(1);
        #pragma unroll
        for (int mi = 0; mi < 2; ++mi)
            #pragma unroll
            for (int ni = 0; ni < 4; ++ni)
                #pragma unroll
                for (int kk = 0; kk < 2; ++kk)
                    acc[mi + 2][ni] = __builtin_amdgcn_mfma_f32_16x16x32_bf16(
                        af2[kk][mi], bfg[kk][ni], acc[mi + 2][ni], 0, 0, 0);
        __builtin_amdgcn_s_setprio(0);
        if (doPre) asm volatile("s_waitcnt vmcnt(6)" ::: "memory");
        else       asm volatile("s_waitcnt vmcnt(0)" ::: "memory");
        __builtin_amdgcn_s_barrier();

        cur = (cur == 2) ? 0 : cur + 1;
        pre = (pre == 2) ? 0 : pre + 1;
        kpre += 64;
    }

    // epilogue: C/D layout col = lane&15, row = (lane>>4)*4 + j  [m89]
    const int mbase = row0a + wm * 64 + quad * 4;
    const int nbase = row0b + wn * 64 + r;
    #pragma unroll
    for (int mi = 0; mi < 4; ++mi) {
        #pragma unroll
        for (int ni = 0; ni < 4; ++ni) {
            const int n = nbase + ni * 16;
            const float bv = bias[n];
            #pragma unroll
            for (int j = 0; j < 4; ++j) {
                const int m = mbase + mi * 16 + j;
                float c = acc[mi][ni][j] + bv;
                const size_t idx = (size_t)m * N + n;
                if constexpr (EPI == 1) {
                    c = 0.5f * c * (1.0f + erff(c * 0.70710678118654752f));
                }
                if constexpr (EPI == 2) {
                    outf[idx] = c + res[idx];
                } else {
                    outb[idx] = f2b(c);
                }
            }
        }
    }
}

extern "C" void kernel_launch(void* const* d_in, const int* in_sizes, int n_in,
                              void* d_out, int out_size, void* d_ws, size_t ws_size,
                              hipStream_t stream) {
    const float* x     = (const float*)d_in[0];
    const unsigned char* kpm = (const unsigned char*)d_in[1];
    const float* w_qkv = (const float*)d_in[2];
    const float* b_qkv = (const float*)d_in[3];
    const float* w_out = (const float*)d_in[4];
    const float* b_out = (const float*)d_in[5];
    const float* ln1_g = (const float*)d_in[6];
    const float* ln1_b = (const float*)d_in[7];
    const float* ln2_g = (const float*)d_in[8];
    const float* ln2_b = (const float*)d_in[9];
    const float* w1    = (const float*)d_in[10];
    const float* b1    = (const float*)d_in[11];
    const float* w2    = (const float*)d_in[12];
    const float* b2    = (const float*)d_in[13];
    float* out = (float*)d_out;

    if (ws_size < WS_REQUIRED) {
        int n = out_size;
        fallback_k<<<(n + 255) / 256, 256, 0, stream>>>(x, out, n);
        return;
    }

    char* ws = (char*)d_ws;
    float* h    = (float*)(ws + OFF_H);
    u16*  Abuf  = (u16*)(ws + OFF_ABUF);
    u16*  Bbuf  = (u16*)(ws + OFF_BBUF);
    u16*  Wbuf  = (u16*)(ws + OFF_WBUF);

    auto conv = [&](const float* src, size_t n) {
        int n4 = (int)(n / 4);
        f2b_k<<<(n4 + 255) / 256, 256, 0, stream>>>(src, Wbuf, n4);
    };

    // h = x
    hipMemcpyAsync(h, x, (size_t)MROWS * DM * sizeof(float),
                   hipMemcpyDeviceToDevice, stream);

    for (int l = 0; l < NL; ++l) {
        // LN1 -> Abuf (bf16)
        ln_k<<<MROWS, 256, 0, stream>>>(h, ln1_g + (size_t)l * DM, ln1_b + (size_t)l * DM, Abuf);
        // QKV: (8192 x 3072) + bias -> Bbuf bf16
        conv(w_qkv + (size_t)l * 3 * DM * DM, (size_t)3 * DM * DM);
        gemm_nt<0><<<dim3(3 * DM / 128, MROWS / 256), 512, 0, stream>>>(
            Abuf, Wbuf, b_qkv + (size_t)l * 3 * DM,
            nullptr, nullptr, Bbuf, MROWS, 3 * DM, DM);
        // banded attention -> Abuf bf16
        attn_k<<<BATCH * NH * (SEQ / 64), 64, 0, stream>>>(Bbuf, kpm, Abuf);
        // out-proj + residual: h += Abuf * w_out^T + b_out  (fp32)
        conv(w_out + (size_t)l * DM * DM, (size_t)DM * DM);
        gemm_nt<2><<<dim3(DM / 128, MROWS / 256), 512, 0, stream>>>(
            Abuf, Wbuf, b_out + (size_t)l * DM,
            h, h, nullptr, MROWS, DM, DM);
        // LN2 -> Abuf (bf16)
        ln_k<<<MROWS, 256, 0, stream>>>(h, ln2_g + (size_t)l * DM, ln2_b + (size_t)l * DM, Abuf);
        // FF1 + exact gelu -> Bbuf bf16  (8192 x 4096)
        conv(w1 + (size_t)l * DFF * DM, (size_t)DFF * DM);
        gemm_nt<1><<<dim3(DFF / 128, MROWS / 256), 512, 0, stream>>>(
            Abuf, Wbuf, b1 + (size_t)l * DFF,
            nullptr, nullptr, Bbuf, MROWS, DFF, DM);
        // FF2 + residual -> h (or d_out on last layer), fp32
        conv(w2 + (size_t)l * DM * DFF, (size_t)DM * DFF);
        float* ff2out = (l == NL - 1) ? out : h;
        gemm_nt<2><<<dim3(DM / 128, MROWS / 256), 512, 0, stream>>>(
            Bbuf, Wbuf, b2 + (size_t)l * DM,
            h, ff2out, nullptr, MROWS, DM, DFF);
    }
}

// Round 15
// 829.570 us; speedup vs baseline: 1.0510x; 1.0510x over previous
//
#include <hip/hip_runtime.h>
#include <cstdint>
#include <cstddef>

typedef unsigned short u16;
typedef __attribute__((ext_vector_type(8))) short bf16x8;
typedef __attribute__((ext_vector_type(4))) float f32x4;

namespace {
constexpr int BATCH = 4;
constexpr int SEQ   = 2048;
constexpr int DM    = 1024;
constexpr int NH    = 16;
constexpr int HDIM  = 64;
constexpr int NL    = 2;
constexpr int DFF   = 4096;
constexpr int MROWS = BATCH * SEQ;   // 8192
constexpr int WIN   = 6;             // band half-width -> 13 keys max

constexpr size_t OFF_H    = 0;                       // 32 MiB fp32 residual
constexpr size_t OFF_ABUF = (size_t)32 << 20;        // 16 MiB bf16 (hn / attn out)
constexpr size_t OFF_BBUF = (size_t)48 << 20;        // 64 MiB bf16 (qkv / ff1)
constexpr size_t OFF_WBUF = (size_t)112 << 20;       //  8 MiB bf16 (per-GEMM weight)
constexpr size_t WS_REQUIRED = (size_t)120 << 20;

constexpr int SLOT = 256 * 64;       // u16 per LDS slot: A 128x64 + B 128x64 = 32 KiB
}

static __device__ __forceinline__ float b2f(u16 u) {
    return __builtin_bit_cast(float, (unsigned int)u << 16);
}
static __device__ __forceinline__ u16 f2b(float f) {
    unsigned int u = __builtin_bit_cast(unsigned int, f);
    u += 0x7FFFu + ((u >> 16) & 1u);   // RNE
    return (u16)(u >> 16);
}

// ---------------- fallback (ws too small): wrong answer but no OOB ----------------
__global__ __launch_bounds__(256) void fallback_k(const float* __restrict__ x,
                                                  float* __restrict__ out, int n) {
    int i = blockIdx.x * 256 + threadIdx.x;
    if (i < n) out[i] = x[i];
}

// ---------------- fp32 -> bf16 weight conversion ----------------
__global__ __launch_bounds__(256) void f2b_k(const float* __restrict__ in,
                                             u16* __restrict__ out, int n4) {
    int i = blockIdx.x * 256 + threadIdx.x;
    if (i < n4) {
        float4 v = ((const float4*)in)[i];
        unsigned int lo = (unsigned int)f2b(v.x) | ((unsigned int)f2b(v.y) << 16);
        unsigned int hi = (unsigned int)f2b(v.z) | ((unsigned int)f2b(v.w) << 16);
        ((uint2*)out)[i] = make_uint2(lo, hi);
    }
}

// ---------------- LayerNorm (row of 1024), fp32 in -> bf16 out ----------------
__global__ __launch_bounds__(256) void ln_k(const float* __restrict__ x,
                                            const float* __restrict__ g,
                                            const float* __restrict__ b,
                                            u16* __restrict__ out) {
    __shared__ float red[8];
    const int row = blockIdx.x;
    const float4 v = ((const float4*)(x + (size_t)row * DM))[threadIdx.x];
    float s1 = v.x + v.y + v.z + v.w;
    float s2 = v.x * v.x + v.y * v.y + v.z * v.z + v.w * v.w;
    #pragma unroll
    for (int o = 32; o; o >>= 1) {
        s1 += __shfl_xor(s1, o);
        s2 += __shfl_xor(s2, o);
    }
    const int wid = threadIdx.x >> 6, lane = threadIdx.x & 63;
    if (lane == 0) { red[wid] = s1; red[4 + wid] = s2; }
    __syncthreads();
    s1 = red[0] + red[1] + red[2] + red[3];
    s2 = red[4] + red[5] + red[6] + red[7];
    const float mu  = s1 * (1.0f / DM);
    const float var = s2 * (1.0f / DM) - mu * mu;
    const float inv = rsqrtf(var + 1e-5f);
    const float4 gg = ((const float4*)g)[threadIdx.x];
    const float4 bb = ((const float4*)b)[threadIdx.x];
    unsigned int lo = (unsigned int)f2b((v.x - mu) * inv * gg.x + bb.x)
                    | ((unsigned int)f2b((v.y - mu) * inv * gg.y + bb.y) << 16);
    unsigned int hi = (unsigned int)f2b((v.z - mu) * inv * gg.z + bb.z)
                    | ((unsigned int)f2b((v.w - mu) * inv * gg.w + bb.w) << 16);
    ((uint2*)(out + (size_t)row * DM))[threadIdx.x] = make_uint2(lo, hi);
}

// ---------------- banded attention v2: lane = query, serial in-lane dots ----------
__global__ __launch_bounds__(64, 2) void attn_k(const u16* __restrict__ qkv,
                                                const unsigned char* __restrict__ kpm,
                                                u16* __restrict__ out) {
    __shared__ u16 kv[76 * 68];        // 76 rows x 64 dims, row stride 68 u16 (136B)
    __shared__ float p_s[13 * 64];
    const int lane = threadIdx.x;      // query within tile
    const int bid  = blockIdx.x;
    const int qt = bid & (SEQ / 64 - 1);         // 32 tiles
    const int h  = (bid >> 5) & (NH - 1);
    const int b  = bid >> 9;
    const int t0 = qt * 64;
    const int t  = t0 + lane;
    const size_t rstride = 3 * DM;

    const u16* qbase = qkv + ((size_t)b * SEQ + t) * rstride + h * HDIM;
    float q[64];
    #pragma unroll
    for (int c = 0; c < 8; ++c) {
        uint4 v = *(const uint4*)(qbase + c * 8);
        unsigned int w0 = v.x, w1 = v.y, w2 = v.z, w3 = v.w;
        q[c*8+0] = b2f((u16)(w0 & 0xffff)) * 0.125f;
        q[c*8+1] = b2f((u16)(w0 >> 16))    * 0.125f;
        q[c*8+2] = b2f((u16)(w1 & 0xffff)) * 0.125f;
        q[c*8+3] = b2f((u16)(w1 >> 16))    * 0.125f;
        q[c*8+4] = b2f((u16)(w2 & 0xffff)) * 0.125f;
        q[c*8+5] = b2f((u16)(w2 >> 16))    * 0.125f;
        q[c*8+6] = b2f((u16)(w3 & 0xffff)) * 0.125f;
        q[c*8+7] = b2f((u16)(w3 >> 16))    * 0.125f;
    }

    auto stage = [&](int which) {
        const u16* src0 = qkv + ((size_t)b * SEQ) * rstride + which * DM + h * HDIM;
        #pragma unroll
        for (int it = 0; it < 10; ++it) {
            int g = it * 64 + lane;                // 16B chunk id, 608 total
            if (g < 608) {
                int row = g >> 3, cc = g & 7;
                int j = t0 - 6 + row;
                j = min(max(j, 0), SEQ - 1);
                uint4 v = *(const uint4*)(src0 + (size_t)j * rstride + cc * 8);
                *(uint2*)(kv + row * 68 + cc * 8)     = make_uint2(v.x, v.y);
                *(uint2*)(kv + row * 68 + cc * 8 + 4) = make_uint2(v.z, v.w);
            }
        }
    };

    stage(1);
    __syncthreads();
    for (int u = 0; u < 13; ++u) {
        const u16* krow = kv + (lane + u) * 68;
        float s = 0.f;
        #pragma unroll
        for (int c = 0; c < 16; ++c) {
            uint2 v = *(const uint2*)(krow + c * 4);
            s += q[c*4+0] * b2f((u16)(v.x & 0xffff));
            s += q[c*4+1] * b2f((u16)(v.x >> 16));
            s += q[c*4+2] * b2f((u16)(v.y & 0xffff));
            s += q[c*4+3] * b2f((u16)(v.y >> 16));
        }
        int j = t - WIN + u;
        bool ok = (j >= 0) && (j < SEQ);
        if (ok && kpm[b * SEQ + j]) ok = false;
        p_s[u * 64 + lane] = ok ? s : -1e30f;
    }

    float mx = -1e30f;
    for (int u = 0; u < 13; ++u) mx = fmaxf(mx, p_s[u * 64 + lane]);
    float den = 0.f;
    for (int u = 0; u < 13; ++u) {
        float e = __expf(p_s[u * 64 + lane] - mx);
        p_s[u * 64 + lane] = e;
        den += e;
    }
    const float inv = 1.0f / den;

    __syncthreads();
    stage(2);
    __syncthreads();
    u16* orow = out + ((size_t)b * SEQ + t) * DM + h * HDIM;
    #pragma unroll
    for (int dc = 0; dc < 4; ++dc) {
        float o[16] = {};
        for (int u = 0; u < 13; ++u) {
            const float p = p_s[u * 64 + lane];
            const u16* vrow = kv + (lane + u) * 68 + dc * 16;
            #pragma unroll
            for (int c = 0; c < 4; ++c) {
                uint2 v = *(const uint2*)(vrow + c * 4);
                o[c*4+0] += p * b2f((u16)(v.x & 0xffff));
                o[c*4+1] += p * b2f((u16)(v.x >> 16));
                o[c*4+2] += p * b2f((u16)(v.y & 0xffff));
                o[c*4+3] += p * b2f((u16)(v.y >> 16));
            }
        }
        unsigned int pk[8];
        #pragma unroll
        for (int i = 0; i < 8; ++i)
            pk[i] = (unsigned int)f2b(o[2*i] * inv)
                  | ((unsigned int)f2b(o[2*i+1] * inv) << 16);
        *(uint4*)(orow + dc * 16)     = make_uint4(pk[0], pk[1], pk[2], pk[3]);
        *(uint4*)(orow + dc * 16 + 8) = make_uint4(pk[4], pk[5], pk[6], pk[7]);
    }
}

// ---------------- bf16 NT GEMM v4: 128x128 tile, BK=64, 2-slot double buffer ------
// T3-minimum 2-phase (catalog recipe): issue STAGE(t+1) into the other slot BEFORE
// computing tile t; one vmcnt(0)+barrier per iteration. 64 KiB LDS -> 2 blocks/CU
// (restores the cross-block overlap v3 lost at 144 KiB / 1 block/CU). Precomputed
// staging addresses (v3's proven VALU win). T2 swizzle: linear global_load_lds dest,
// inverse-swizzled source, XOR'd read (rule #21). No setprio (T5 null w/o 8-phase).
// EPI 0: +bias -> bf16 ; EPI 1: +bias, exact gelu -> bf16 ; EPI 2: +bias, +res -> fp32
template <int EPI>
__global__ __launch_bounds__(256, 2) void gemm_nt(const u16* __restrict__ A,
                                                  const u16* __restrict__ Bw,
                                                  const float* __restrict__ bias,
                                                  const float* __restrict__ res,
                                                  float* __restrict__ outf,
                                                  u16* __restrict__ outb,
                                                  int M, int N, int K) {
    __shared__ u16 lds[2 * SLOT];      // 64 KiB
    const int tid  = threadIdx.x;
    const int lane = tid & 63;
    const int wid  = tid >> 6;         // 0..3
    const int wm = wid >> 1, wn = wid & 1;
    const int r = lane & 15, quad = lane >> 4;
    const int row0a = blockIdx.y * 128;
    const int row0b = blockIdx.x * 128;
    const int nt = K >> 6;

    // precomputed staging sources/dests (8 x 16B chunks per thread per K-tile)
    const u16* gsrc[8];
    int dofs[8];
    #pragma unroll
    for (int s4 = 0; s4 < 4; ++s4) {           // A: 128x64 = 1024 chunks
        int e8 = s4 * 256 + tid;
        int rw = e8 >> 3, sl = e8 & 7, ssl = sl ^ (rw & 7);
        gsrc[s4] = A + (size_t)(row0a + rw) * K + ssl * 8;
        dofs[s4] = e8 * 8;
    }
    #pragma unroll
    for (int s4 = 0; s4 < 4; ++s4) {           // B: 128x64 = 1024 chunks
        int e8 = s4 * 256 + tid;
        int rw = e8 >> 3, sl = e8 & 7, ssl = sl ^ (rw & 7);
        gsrc[4 + s4] = Bw + (size_t)(row0b + rw) * K + ssl * 8;
        dofs[4 + s4] = 128 * 64 + e8 * 8;
    }
    auto stage = [&](u16* base, int k0) {
        #pragma unroll
        for (int i = 0; i < 8; ++i)
            __builtin_amdgcn_global_load_lds(
                (const __attribute__((address_space(1))) void*)(gsrc[i] + k0),
                (__attribute__((address_space(3))) void*)(base + dofs[i]), 16, 0, 0);
    };

    // prologue: stage tile 0 into slot 0
    stage(lds, 0);
    asm volatile("s_waitcnt vmcnt(0)" ::: "memory");
    __builtin_amdgcn_s_barrier();

    f32x4 acc[4][4] = {};
    int cur = 0;
    for (int t = 0; t < nt; ++t) {
        const u16* As = lds + cur * SLOT;
        const u16* Bs = As + 128 * 64;
        if (t + 1 < nt) stage(lds + (cur ^ 1) * SLOT, (t + 1) * 64);

        #pragma unroll
        for (int kk = 0; kk < 2; ++kk) {
            bf16x8 af[4], bfg[4];
            #pragma unroll
            for (int mi = 0; mi < 4; ++mi) {
                int rw = wm * 64 + mi * 16 + r;
                int sl = (kk * 4 + quad) ^ (rw & 7);
                af[mi] = *(const bf16x8*)(As + rw * 64 + sl * 8);
            }
            #pragma unroll
            for (int ni = 0; ni < 4; ++ni) {
                int rw = wn * 64 + ni * 16 + r;
                int sl = (kk * 4 + quad) ^ (rw & 7);
                bfg[ni] = *(const bf16x8*)(Bs + rw * 64 + sl * 8);
            }
            #pragma unroll
            for (int mi = 0; mi < 4; ++mi)
                #pragma unroll
                for (int ni = 0; ni < 4; ++ni)
                    acc[mi][ni] = __builtin_amdgcn_mfma_f32_16x16x32_bf16(
                        af[mi], bfg[ni], acc[mi][ni], 0, 0, 0);
        }
        asm volatile("s_waitcnt vmcnt(0)" ::: "memory");
        __builtin_amdgcn_s_barrier();
        cur ^= 1;
    }

    // epilogue: C/D layout col = lane&15, row = (lane>>4)*4 + j  [m89]
    const int mbase = row0a + wm * 64 + quad * 4;
    const int nbase = row0b + wn * 64 + r;
    #pragma unroll
    for (int mi = 0; mi < 4; ++mi) {
        #pragma unroll
        for (int ni = 0; ni < 4; ++ni) {
            const int n = nbase + ni * 16;
            const float bv = bias[n];
            #pragma unroll
            for (int j = 0; j < 4; ++j) {
                const int m = mbase + mi * 16 + j;
                float c = acc[mi][ni][j] + bv;
                const size_t idx = (size_t)m * N + n;
                if constexpr (EPI == 1) {
                    c = 0.5f * c * (1.0f + erff(c * 0.70710678118654752f));
                }
                if constexpr (EPI == 2) {
                    outf[idx] = c + res[idx];
                } else {
                    outb[idx] = f2b(c);
                }
            }
        }
    }
}

extern "C" void kernel_launch(void* const* d_in, const int* in_sizes, int n_in,
                              void* d_out, int out_size, void* d_ws, size_t ws_size,
                              hipStream_t stream) {
    const float* x     = (const float*)d_in[0];
    const unsigned char* kpm = (const unsigned char*)d_in[1];
    const float* w_qkv = (const float*)d_in[2];
    const float* b_qkv = (const float*)d_in[3];
    const float* w_out = (const float*)d_in[4];
    const float* b_out = (const float*)d_in[5];
    const float* ln1_g = (const float*)d_in[6];
    const float* ln1_b = (const float*)d_in[7];
    const float* ln2_g = (const float*)d_in[8];
    const float* ln2_b = (const float*)d_in[9];
    const float* w1    = (const float*)d_in[10];
    const float* b1    = (const float*)d_in[11];
    const float* w2    = (const float*)d_in[12];
    const float* b2    = (const float*)d_in[13];
    float* out = (float*)d_out;

    if (ws_size < WS_REQUIRED) {
        int n = out_size;
        fallback_k<<<(n + 255) / 256, 256, 0, stream>>>(x, out, n);
        return;
    }

    char* ws = (char*)d_ws;
    float* h    = (float*)(ws + OFF_H);
    u16*  Abuf  = (u16*)(ws + OFF_ABUF);
    u16*  Bbuf  = (u16*)(ws + OFF_BBUF);
    u16*  Wbuf  = (u16*)(ws + OFF_WBUF);

    auto conv = [&](const float* src, size_t n) {
        int n4 = (int)(n / 4);
        f2b_k<<<(n4 + 255) / 256, 256, 0, stream>>>(src, Wbuf, n4);
    };

    // h = x
    hipMemcpyAsync(h, x, (size_t)MROWS * DM * sizeof(float),
                   hipMemcpyDeviceToDevice, stream);

    for (int l = 0; l < NL; ++l) {
        // LN1 -> Abuf (bf16)
        ln_k<<<MROWS, 256, 0, stream>>>(h, ln1_g + (size_t)l * DM, ln1_b + (size_t)l * DM, Abuf);
        // QKV: (8192 x 3072) + bias -> Bbuf bf16
        conv(w_qkv + (size_t)l * 3 * DM * DM, (size_t)3 * DM * DM);
        gemm_nt<0><<<dim3(3 * DM / 128, MROWS / 128), 256, 0, stream>>>(
            Abuf, Wbuf, b_qkv + (size_t)l * 3 * DM,
            nullptr, nullptr, Bbuf, MROWS, 3 * DM, DM);
        // banded attention -> Abuf bf16
        attn_k<<<BATCH * NH * (SEQ / 64), 64, 0, stream>>>(Bbuf, kpm, Abuf);
        // out-proj + residual: h += Abuf * w_out^T + b_out  (fp32)
        conv(w_out + (size_t)l * DM * DM, (size_t)DM * DM);
        gemm_nt<2><<<dim3(DM / 128, MROWS / 128), 256, 0, stream>>>(
            Abuf, Wbuf, b_out + (size_t)l * DM,
            h, h, nullptr, MROWS, DM, DM);
        // LN2 -> Abuf (bf16)
        ln_k<<<MROWS, 256, 0, stream>>>(h, ln2_g + (size_t)l * DM, ln2_b + (size_t)l * DM, Abuf);
        // FF1 + exact gelu -> Bbuf bf16  (8192 x 4096)
        conv(w1 + (size_t)l * DFF * DM, (size_t)DFF * DM);
        gemm_nt<1><<<dim3(DFF / 128, MROWS / 128), 256, 0, stream>>>(
            Abuf, Wbuf, b1 + (size_t)l * DFF,
            nullptr, nullptr, Bbuf, MROWS, DFF, DM);
        // FF2 + residual -> h (or d_out on last layer), fp32
        conv(w2 + (size_t)l * DM * DFF, (size_t)DM * DFF);
        float* ff2out = (l == NL - 1) ? out : h;
        gemm_nt<2><<<dim3(DM / 128, MROWS / 128), 256, 0, stream>>>(
            Bbuf, Wbuf, b2 + (size_t)l * DM,
            h, ff2out, nullptr, MROWS, DM, DFF);
    }
}